// Round 6
// baseline (1070.838 us; speedup 1.0000x reference)
//
#include <hip/hip_runtime.h>
#include <hip/hip_cooperative_groups.h>
#include <cmath>

namespace cg = cooperative_groups;

// B=64, L=512, H=64, 2H=128, OUT=5
static constexpr int kB = 64, kL = 512, kH = 64, kH2 = 128, kOut = 5;

typedef short bf16x8 __attribute__((ext_vector_type(8)));
typedef float f32x4  __attribute__((ext_vector_type(4)));

__device__ __forceinline__ unsigned short f2bf(float f) {
  unsigned u = __float_as_uint(f);
  unsigned r = (u + 0x7FFFu + ((u >> 16) & 1u)) >> 16;   // RNE
  return (unsigned short)r;
}

__device__ __forceinline__ void cvt8(const f32x4& v0, const f32x4& v1,
                                     bf16x8& hi, bf16x8& lo) {
  #pragma unroll
  for (int j = 0; j < 4; ++j) {
    unsigned short h0 = f2bf(v0[j]);
    unsigned short h1 = f2bf(v1[j]);
    hi[j]     = (short)h0;
    hi[j + 4] = (short)h1;
    lo[j]     = (short)f2bf(v0[j] - __uint_as_float(((unsigned)h0) << 16));
    lo[j + 4] = (short)f2bf(v1[j] - __uint_as_float(((unsigned)h1) << 16));
  }
}

// ---- prepass: V fp32 -> bf16 (row-major [i][p][q]); W -> Wt bf16 [i][p] ----
__global__ void prep_k(const float* __restrict__ V, const float* __restrict__ W,
                       unsigned short* __restrict__ vhi, unsigned short* __restrict__ wt) {
  int idx = blockIdx.x * 256 + threadIdx.x;
  if (idx < kH * kH2 * kH2) {
    vhi[idx] = f2bf(V[idx]);
  } else {
    int widx = idx - kH * kH2 * kH2;
    if (widx < kH * kH2) {
      int i = widx >> 7, p = widx & 127;
      wt[widx] = f2bf(W[p * kH + i]);      // Wt[i][p] = W[p][i]
    }
  }
}

// ---- unit body (non-first level): one 128-node tile x IS i-values ----
// Identical math/structure to the measured-best R2 staged kernel.
__device__ __forceinline__ void unit_body(
    const float* __restrict__ in, const unsigned short* __restrict__ vhi,
    const unsigned short* __restrict__ wt, const float* __restrict__ bias,
    float* __restrict__ out, int M, int IS, int m0, int i0,
    unsigned short* Vs, float* res)
{
  const int t = threadIdx.x;
  const int lane = t & 63, w = t >> 6;
  const int c = lane & 15, q = lane >> 4;
  const int Mrows = (M < 128) ? M : 128;
  const bool has_rows = (w * 32) < Mrows;

  bf16x8 bh[2][4], bl[2][4];
  f32x4  Cred[2][8];

  if (has_rows) {
    #pragma unroll
    for (int mt = 0; mt < 2; ++mt) {
      int m = m0 + w * 32 + mt * 16 + c;
      const float* crow = in + (size_t)m * kH2;
      #pragma unroll
      for (int ks = 0; ks < 4; ++ks) {
        const float* src = crow + ks * 32 + q * 8;
        f32x4 v0 = *(const f32x4*)src;
        f32x4 v1 = *(const f32x4*)(src + 4);
        cvt8(v0, v1, bh[mt][ks], bl[mt][ks]);
      }
      #pragma unroll
      for (int pt = 0; pt < 8; ++pt) {
        Cred[mt][pt] = *(const f32x4*)(crow + pt * 16 + q * 4);
      }
    }
    // Wx GEMM: res = Wx + bias
    {
      int irow = i0 + c; if (irow > 63) irow = 63;
      f32x4 ah0 = {0.f,0.f,0.f,0.f}, al0 = ah0, ah1 = ah0, al1 = ah0;
      #pragma unroll
      for (int ks = 0; ks < 4; ++ks) {
        bf16x8 a = *(const bf16x8*)(wt + (size_t)irow * kH2 + ks * 32 + q * 8);
        ah0 = __builtin_amdgcn_mfma_f32_16x16x32_bf16(a, bh[0][ks], ah0, 0, 0, 0);
        al0 = __builtin_amdgcn_mfma_f32_16x16x32_bf16(a, bl[0][ks], al0, 0, 0, 0);
        ah1 = __builtin_amdgcn_mfma_f32_16x16x32_bf16(a, bh[1][ks], ah1, 0, 0, 0);
        al1 = __builtin_amdgcn_mfma_f32_16x16x32_bf16(a, bl[1][ks], al1, 0, 0, 0);
      }
      #pragma unroll
      for (int reg = 0; reg < 4; ++reg) {
        int ii = q * 4 + reg;
        if (ii < IS) {
          float bv = bias[i0 + ii];
          res[(w * 32 + c) * 17 + ii]      = ah0[reg] + al0[reg] + bv;
          res[(w * 32 + 16 + c) * 17 + ii] = ah1[reg] + al1[reg] + bv;
        }
      }
    }
  }

  auto stageV = [&](int i) {
    const unsigned short* vsrc = vhi + (size_t)i * (kH2 * kH2);
    #pragma unroll
    for (int r = 0; r < 8; ++r) {
      int chunk = w * 512 + r * 64 + lane;
      int p  = chunk >> 4;
      int pc = chunk & 15;
      int cc = pc ^ (p & 7);
      const unsigned short* g = vsrc + p * kH2 + cc * 8;
      __builtin_amdgcn_global_load_lds(
          (const __attribute__((address_space(1))) unsigned int*)g,
          (__attribute__((address_space(3))) unsigned int*)
              ((char*)&Vs[0] + (size_t)(w * 512 + r * 64) * 16),
          16, 0, 0);
    }
  };

  stageV(i0);
  __syncthreads();

  for (int ic = 0; ic < IS; ++ic) {
    if (has_rows) {
      float g0 = 0.f, g1 = 0.f;
      for (int pt = 0; pt < 8; ++pt) {
        f32x4 a0 = {0.f,0.f,0.f,0.f}, a1 = a0, a2 = a0, a3 = a0;
        #pragma unroll
        for (int ks = 0; ks < 4; ++ks) {
          int p  = pt * 16 + c;
          int cc = (ks * 4 + q) ^ (p & 7);
          bf16x8 vf = *(const bf16x8*)((const char*)&Vs[0] + (size_t)p * 256 + cc * 16);
          a0 = __builtin_amdgcn_mfma_f32_16x16x32_bf16(vf, bh[0][ks], a0, 0, 0, 0);
          a1 = __builtin_amdgcn_mfma_f32_16x16x32_bf16(vf, bl[0][ks], a1, 0, 0, 0);
          a2 = __builtin_amdgcn_mfma_f32_16x16x32_bf16(vf, bh[1][ks], a2, 0, 0, 0);
          a3 = __builtin_amdgcn_mfma_f32_16x16x32_bf16(vf, bl[1][ks], a3, 0, 0, 0);
        }
        f32x4 d0 = a0 + a1, d1 = a2 + a3;
        f32x4 cr0 = Cred[0][pt], cr1 = Cred[1][pt];
        g0 = fmaf(cr0[0], d0[0], g0); g0 = fmaf(cr0[1], d0[1], g0);
        g0 = fmaf(cr0[2], d0[2], g0); g0 = fmaf(cr0[3], d0[3], g0);
        g1 = fmaf(cr1[0], d1[0], g1); g1 = fmaf(cr1[1], d1[1], g1);
        g1 = fmaf(cr1[2], d1[2], g1); g1 = fmaf(cr1[3], d1[3], g1);
      }
      g0 += __shfl_xor(g0, 16); g0 += __shfl_xor(g0, 32);
      g1 += __shfl_xor(g1, 16); g1 += __shfl_xor(g1, 32);
      if (q == 0)      res[(w * 32 + c) * 17 + ic]      += g0;
      else if (q == 1) res[(w * 32 + 16 + c) * 17 + ic] += g1;
    }
    __syncthreads();
    if (ic + 1 < IS) { stageV(i0 + ic + 1); __syncthreads(); }
  }

  const int sh = __builtin_ctz(IS);
  for (int idx = t; idx < Mrows * IS; idx += 256) {
    int m = idx >> sh, ii = idx & (IS - 1);
    out[(size_t)(m0 + m) * kH + i0 + ii] = tanhf(res[m * 17 + ii]);
  }
}

// ---- L1 (FIRST): measured-best R2 structure, gathers from embed ----
__global__ __launch_bounds__(256) void combine_first_k(
    const int* __restrict__ tokens, const float* __restrict__ embed,
    const unsigned short* __restrict__ vhi, const unsigned short* __restrict__ wt,
    const float* __restrict__ bias, float* __restrict__ out, int M, int IS)
{
  __shared__ unsigned short Vs[kH2 * kH2];
  __shared__ float res[128 * 17];

  const int t = threadIdx.x;
  const int lane = t & 63, w = t >> 6;
  const int c = lane & 15, q = lane >> 4;
  const int m0 = (int)blockIdx.x * 128;
  const int i0 = (int)blockIdx.y * IS;
  const bool has_rows = true;                // M=16384, all tiles full

  bf16x8 bh[2][4], bl[2][4];
  f32x4  Cred[2][8];

  if (has_rows) {
    #pragma unroll
    for (int mt = 0; mt < 2; ++mt) {
      int m = m0 + w * 32 + mt * 16 + c;
      int b = m >> 8, j = m & 255;           // Nout=256
      int tokA = tokens[b * kL + 2 * j];
      int tokB = tokens[b * kL + 2 * j + 1];
      #pragma unroll
      for (int ks = 0; ks < 4; ++ks) {
        int q0 = ks * 32 + q * 8;
        const float* src = embed + (size_t)(q0 < 64 ? tokA : tokB) * kH + (q0 & 63);
        f32x4 v0 = *(const f32x4*)src;
        f32x4 v1 = *(const f32x4*)(src + 4);
        cvt8(v0, v1, bh[mt][ks], bl[mt][ks]);
      }
      #pragma unroll
      for (int pt = 0; pt < 8; ++pt) {
        int p0 = pt * 16 + q * 4;
        const float* src = embed + (size_t)(p0 < 64 ? tokA : tokB) * kH + (p0 & 63);
        Cred[mt][pt] = *(const f32x4*)src;
      }
    }
    {
      int irow = i0 + c; if (irow > 63) irow = 63;
      f32x4 ah0 = {0.f,0.f,0.f,0.f}, al0 = ah0, ah1 = ah0, al1 = ah0;
      #pragma unroll
      for (int ks = 0; ks < 4; ++ks) {
        bf16x8 a = *(const bf16x8*)(wt + (size_t)irow * kH2 + ks * 32 + q * 8);
        ah0 = __builtin_amdgcn_mfma_f32_16x16x32_bf16(a, bh[0][ks], ah0, 0, 0, 0);
        al0 = __builtin_amdgcn_mfma_f32_16x16x32_bf16(a, bl[0][ks], al0, 0, 0, 0);
        ah1 = __builtin_amdgcn_mfma_f32_16x16x32_bf16(a, bh[1][ks], ah1, 0, 0, 0);
        al1 = __builtin_amdgcn_mfma_f32_16x16x32_bf16(a, bl[1][ks], al1, 0, 0, 0);
      }
      #pragma unroll
      for (int reg = 0; reg < 4; ++reg) {
        int ii = q * 4 + reg;
        if (ii < IS) {
          float bv = bias[i0 + ii];
          res[(w * 32 + c) * 17 + ii]      = ah0[reg] + al0[reg] + bv;
          res[(w * 32 + 16 + c) * 17 + ii] = ah1[reg] + al1[reg] + bv;
        }
      }
    }
  }

  auto stageV = [&](int i) {
    const unsigned short* vsrc = vhi + (size_t)i * (kH2 * kH2);
    #pragma unroll
    for (int r = 0; r < 8; ++r) {
      int chunk = w * 512 + r * 64 + lane;
      int p  = chunk >> 4;
      int pc = chunk & 15;
      int cc = pc ^ (p & 7);
      const unsigned short* g = vsrc + p * kH2 + cc * 8;
      __builtin_amdgcn_global_load_lds(
          (const __attribute__((address_space(1))) unsigned int*)g,
          (__attribute__((address_space(3))) unsigned int*)
              ((char*)&Vs[0] + (size_t)(w * 512 + r * 64) * 16),
          16, 0, 0);
    }
  };

  stageV(i0);
  __syncthreads();

  for (int ic = 0; ic < IS; ++ic) {
    {
      float g0 = 0.f, g1 = 0.f;
      for (int pt = 0; pt < 8; ++pt) {
        f32x4 a0 = {0.f,0.f,0.f,0.f}, a1 = a0, a2 = a0, a3 = a0;
        #pragma unroll
        for (int ks = 0; ks < 4; ++ks) {
          int p  = pt * 16 + c;
          int cc = (ks * 4 + q) ^ (p & 7);
          bf16x8 vf = *(const bf16x8*)((const char*)&Vs[0] + (size_t)p * 256 + cc * 16);
          a0 = __builtin_amdgcn_mfma_f32_16x16x32_bf16(vf, bh[0][ks], a0, 0, 0, 0);
          a1 = __builtin_amdgcn_mfma_f32_16x16x32_bf16(vf, bl[0][ks], a1, 0, 0, 0);
          a2 = __builtin_amdgcn_mfma_f32_16x16x32_bf16(vf, bh[1][ks], a2, 0, 0, 0);
          a3 = __builtin_amdgcn_mfma_f32_16x16x32_bf16(vf, bl[1][ks], a3, 0, 0, 0);
        }
        f32x4 d0 = a0 + a1, d1 = a2 + a3;
        f32x4 cr0 = Cred[0][pt], cr1 = Cred[1][pt];
        g0 = fmaf(cr0[0], d0[0], g0); g0 = fmaf(cr0[1], d0[1], g0);
        g0 = fmaf(cr0[2], d0[2], g0); g0 = fmaf(cr0[3], d0[3], g0);
        g1 = fmaf(cr1[0], d1[0], g1); g1 = fmaf(cr1[1], d1[1], g1);
        g1 = fmaf(cr1[2], d1[2], g1); g1 = fmaf(cr1[3], d1[3], g1);
      }
      g0 += __shfl_xor(g0, 16); g0 += __shfl_xor(g0, 32);
      g1 += __shfl_xor(g1, 16); g1 += __shfl_xor(g1, 32);
      if (q == 0)      res[(w * 32 + c) * 17 + ic]      += g0;
      else if (q == 1) res[(w * 32 + 16 + c) * 17 + ic] += g1;
    }
    __syncthreads();
    if (ic + 1 < IS) { stageV(i0 + ic + 1); __syncthreads(); }
  }

  const int sh = __builtin_ctz(IS);
  for (int idx = t; idx < 128 * IS; idx += 256) {
    int m = idx >> sh, ii = idx & (IS - 1);
    out[(size_t)(m0 + m) * kH + i0 + ii] = tanhf(res[m * 17 + ii]);
  }
}

// ---- fused levels 2..9 + head: one cooperative kernel, grid.sync between ----
__global__ __launch_bounds__(256) void fused_tail_k(
    float* bufA, float* bufB, const unsigned short* __restrict__ vhi,
    const unsigned short* __restrict__ wt, const float* __restrict__ bias,
    const float* __restrict__ Wout, const float* __restrict__ bout,
    float* __restrict__ out)
{
  __shared__ unsigned short Vs[kH2 * kH2];
  __shared__ float res[128 * 17];
  cg::grid_group grid = cg::this_grid();

  float* cur = bufA;   // L1 output
  float* nxt = bufB;
  for (int Nout = 128; Nout >= 1; Nout >>= 1) {
    int M = kB * Nout;
    int gx = (M + 127) / 128;
    int IS = gx / 8; if (IS < 1) IS = 1; if (IS > 16) IS = 16;
    int gy = 64 / IS;
    int U = gx * gy;
    for (int u = blockIdx.x; u < U; u += gridDim.x) {
      int mtile = u % gx, ichunk = u / gx;
      __syncthreads();
      unit_body(cur, vhi, wt, bias, nxt, M, IS, mtile * 128, ichunk * IS, Vs, res);
    }
    __threadfence();
    grid.sync();
    float* tmp = cur; cur = nxt; nxt = tmp;
  }
  // head on block 0: logits = root @ Wout + bout; log_softmax
  if (blockIdx.x == 0 && threadIdx.x < kB) {
    int b = threadIdx.x;
    float l[kOut];
    #pragma unroll
    for (int o = 0; o < kOut; ++o) l[o] = bout[o];
    for (int h = 0; h < kH; ++h) {
      float r = cur[b * kH + h];
      #pragma unroll
      for (int o = 0; o < kOut; ++o) l[o] = fmaf(r, Wout[h * kOut + o], l[o]);
    }
    float mx = l[0];
    #pragma unroll
    for (int o = 1; o < kOut; ++o) mx = fmaxf(mx, l[o]);
    float s = 0.f;
    #pragma unroll
    for (int o = 0; o < kOut; ++o) s += expf(l[o] - mx);
    float lse = logf(s);
    #pragma unroll
    for (int o = 0; o < kOut; ++o) out[b * kOut + o] = l[o] - mx - lse;
  }
}

// ---- fallback (non-cooperative) per-level kernel + head ----
__global__ __launch_bounds__(256) void combine_level_k(
    const float* __restrict__ in, const unsigned short* __restrict__ vhi,
    const unsigned short* __restrict__ wt, const float* __restrict__ bias,
    float* __restrict__ out, int M, int IS)
{
  __shared__ unsigned short Vs[kH2 * kH2];
  __shared__ float res[128 * 17];
  unit_body(in, vhi, wt, bias, out, M, IS,
            (int)blockIdx.x * 128, (int)blockIdx.y * IS, Vs, res);
}

__global__ void head_k(const float* __restrict__ root,
                       const float* __restrict__ Wout,
                       const float* __restrict__ bout,
                       float* __restrict__ out) {
  int b = threadIdx.x;
  float l[kOut];
  #pragma unroll
  for (int o = 0; o < kOut; ++o) l[o] = bout[o];
  for (int h = 0; h < kH; ++h) {
    float r = root[b * kH + h];
    #pragma unroll
    for (int o = 0; o < kOut; ++o) l[o] = fmaf(r, Wout[h * kOut + o], l[o]);
  }
  float mx = l[0];
  #pragma unroll
  for (int o = 1; o < kOut; ++o) mx = fmaxf(mx, l[o]);
  float s = 0.f;
  #pragma unroll
  for (int o = 0; o < kOut; ++o) s += expf(l[o] - mx);
  float lse = logf(s);
  #pragma unroll
  for (int o = 0; o < kOut; ++o) out[b * kOut + o] = l[o] - mx - lse;
}

extern "C" void kernel_launch(void* const* d_in, const int* in_sizes, int n_in,
                              void* d_out, int out_size, void* d_ws, size_t ws_size,
                              hipStream_t stream) {
  const int*   tokens = (const int*)  d_in[0];
  const float* embed  = (const float*)d_in[1];
  const float* V      = (const float*)d_in[2];
  const float* W      = (const float*)d_in[3];
  const float* bias   = (const float*)d_in[4];
  const float* Wout   = (const float*)d_in[5];
  const float* bout   = (const float*)d_in[6];
  float* out = (float*)d_out;

  // ws layout: vhi 2MB | wt 16KB | bufA 4MB | bufB 2MB  (~8.3 MB total)
  char* ws = (char*)d_ws;
  unsigned short* vhi = (unsigned short*)ws;
  unsigned short* wt  = (unsigned short*)(ws + 2097152);
  float* bufA = (float*)(ws + 2097152 + 16384);
  float* bufB = (float*)(ws + 2097152 + 16384 + 4194304);

  int nprep = kH * kH2 * kH2 + kH * kH2;
  prep_k<<<dim3((nprep + 255) / 256), 256, 0, stream>>>(V, W, vhi, wt);

  // L1: M=16384, staged, measured-best structure
  {
    int M = kB * 256, gx = M / 128;          // 128
    int IS = gx / 8; if (IS > 16) IS = 16;   // 16
    dim3 grid(gx, 64 / IS);                  // (128, 4)
    combine_first_k<<<grid, 256, 0, stream>>>(tokens, embed, vhi, wt, bias, bufA, M, IS);
  }

  // L2..L9 + head: single cooperative kernel (512 blocks = 2/CU co-resident)
  {
    float* pA = bufA; float* pB = bufB;
    const unsigned short* pv = vhi; const unsigned short* pw = wt;
    const float* pb = bias; const float* pWo = Wout; const float* pbo = bout;
    float* po = out;
    void* kargs[] = {&pA, &pB, &pv, &pw, &pb, &pWo, &pbo, &po};
    hipError_t ce = hipLaunchCooperativeKernel(fused_tail_k, dim3(512), dim3(256),
                                               kargs, 0, stream);
    if (ce != hipSuccess) {
      // fallback: regular per-level launches (identical math)
      (void)hipGetLastError();               // clear error state
      float* cur = bufA; float* nxt = bufB;
      for (int Nout = 128; Nout >= 1; Nout >>= 1) {
        int M = kB * Nout;
        int gx = (M + 127) / 128;
        int IS = gx / 8; if (IS < 1) IS = 1; if (IS > 16) IS = 16;
        dim3 grid(gx, 64 / IS);
        combine_level_k<<<grid, 256, 0, stream>>>(cur, vhi, wt, bias, nxt, M, IS);
        float* tmp = cur; cur = nxt; nxt = tmp;
      }
      head_k<<<1, 64, 0, stream>>>(cur, Wout, bout, out);
    }
  }
}

// Round 7
// 357.565 us; speedup vs baseline: 2.9948x; 2.9948x over previous
//
#include <hip/hip_runtime.h>
#include <cmath>

// B=64, L=512, H=64, 2H=128, OUT=5
static constexpr int kB = 64, kL = 512, kH = 64, kH2 = 128, kOut = 5;

typedef short bf16x8 __attribute__((ext_vector_type(8)));
typedef float f32x4  __attribute__((ext_vector_type(4)));

__device__ __forceinline__ unsigned short f2bf(float f) {
  unsigned u = __float_as_uint(f);
  unsigned r = (u + 0x7FFFu + ((u >> 16) & 1u)) >> 16;   // RNE
  return (unsigned short)r;
}

__device__ __forceinline__ void cvt8(const f32x4& v0, const f32x4& v1,
                                     bf16x8& hi, bf16x8& lo) {
  #pragma unroll
  for (int j = 0; j < 4; ++j) {
    unsigned short h0 = f2bf(v0[j]);
    unsigned short h1 = f2bf(v1[j]);
    hi[j]     = (short)h0;
    hi[j + 4] = (short)h1;
    lo[j]     = (short)f2bf(v0[j] - __uint_as_float(((unsigned)h0) << 16));
    lo[j + 4] = (short)f2bf(v1[j] - __uint_as_float(((unsigned)h1) << 16));
  }
}

// ---- prepass: V fp32 -> bf16 (row-major [i][p][q]); W -> Wt bf16 [i][p] ----
__global__ void prep_k(const float* __restrict__ V, const float* __restrict__ W,
                       unsigned short* __restrict__ vhi, unsigned short* __restrict__ wt) {
  int idx = blockIdx.x * 256 + threadIdx.x;
  if (idx < kH * kH2 * kH2) {
    vhi[idx] = f2bf(V[idx]);
  } else {
    int widx = idx - kH * kH2 * kH2;
    if (widx < kH * kH2) {
      int i = widx >> 7, p = widx & 127;
      wt[widx] = f2bf(W[p * kH + i]);      // Wt[i][p] = W[p][i]
    }
  }
}

// ---- fused combine level: out[m,i] = tanh(c_m^T V_i c_m + (W^T c_m)_i + b_i)
// MFMA orientation: D[p, m] = sum_q V_i[p,q] * C[m,q]  (A = V_i, B = C hi/lo)
// then R[m,i] = sum_p C[m,p] * D[p,m] via per-lane dot + xor16/xor32 butterfly.
// PIPE SPLIT + PREFETCH: V q-cols 0..63 staged in LDS (16 KB halves,
// double-buffered, 1 barrier/ic); q-cols 64..127 held in VGPRs, prefetched
// ONE ic AHEAD inside the pt-loop so L1 latency hides under ~1200 cyc of
// MFMA+LDS work. Halves the per-CU LDS pipe load (the measured bottleneck)
// without R4's JIT-latency exposure.
template<bool FIRST>
__global__ __launch_bounds__(256) void combine2_k(
    const float* __restrict__ in, const int* __restrict__ tokens,
    const float* __restrict__ embed, const unsigned short* __restrict__ vhi,
    const unsigned short* __restrict__ wt, const float* __restrict__ bias,
    float* __restrict__ out, int M, int IS)
{
  __shared__ unsigned short Vs[2][kH2 * 64]; // 2 x 16 KB halves (q<64), swizzled
  __shared__ float res[128 * 17];            // Wx+bias, then += xVx; pad 17

  const int t = threadIdx.x;
  const int lane = t & 63, w = t >> 6;
  const int c = lane & 15, q = lane >> 4;    // c = B-col (node), q = quad
  const int m0 = (int)blockIdx.x * 128;
  const int i0 = (int)blockIdx.y * IS;
  const int Mrows = (M < 128) ? M : 128;
  const bool has_rows = (w * 32) < Mrows;

  bf16x8 bh[2][4], bl[2][4];   // C hi/lo B-fragments, [mtile][kstep]
  f32x4  Cred[2][8];           // C fp32 for the p-reduction, [mtile][ptile]
  bf16x8 vg[8][2];             // V q-cols 64..127 for CURRENT ic, [pt][ks-2]

  if (has_rows) {
    #pragma unroll
    for (int mt = 0; mt < 2; ++mt) {
      int m = m0 + w * 32 + mt * 16 + c;     // this lane's node row
      const float* crow = nullptr;
      int tokA = 0, tokB = 0;
      if (FIRST) {                           // level 1: gather from embed
        int b = m >> 8, j = m & 255;         // Nout=256
        tokA = tokens[b * kL + 2 * j];
        tokB = tokens[b * kL + 2 * j + 1];
      } else {
        crow = in + (size_t)m * kH2;
      }
      #pragma unroll
      for (int ks = 0; ks < 4; ++ks) {       // B-frag: 8 contiguous q at lane's m
        int q0 = ks * 32 + q * 8;
        const float* src = FIRST
            ? (embed + (size_t)(q0 < 64 ? tokA : tokB) * kH + (q0 & 63))
            : (crow + q0);
        f32x4 v0 = *(const f32x4*)src;
        f32x4 v1 = *(const f32x4*)(src + 4);
        cvt8(v0, v1, bh[mt][ks], bl[mt][ks]);
      }
      #pragma unroll
      for (int pt = 0; pt < 8; ++pt) {       // reduction copy: C[m, pt*16+q*4 ..+4]
        int p0 = pt * 16 + q * 4;
        const float* src = FIRST
            ? (embed + (size_t)(p0 < 64 ? tokA : tokB) * kH + (p0 & 63))
            : (crow + p0);
        Cred[mt][pt] = *(const f32x4*)src;
      }
    }
    // Wx GEMM: D'[i, m] = sum_p Wt[i,p] * C[m,p]; res init = Wx + bias
    {
      int irow = i0 + c; if (irow > 63) irow = 63;
      f32x4 ah0 = {0.f,0.f,0.f,0.f}, al0 = ah0, ah1 = ah0, al1 = ah0;
      #pragma unroll
      for (int ks = 0; ks < 4; ++ks) {
        bf16x8 a = *(const bf16x8*)(wt + (size_t)irow * kH2 + ks * 32 + q * 8);
        ah0 = __builtin_amdgcn_mfma_f32_16x16x32_bf16(a, bh[0][ks], ah0, 0, 0, 0);
        al0 = __builtin_amdgcn_mfma_f32_16x16x32_bf16(a, bl[0][ks], al0, 0, 0, 0);
        ah1 = __builtin_amdgcn_mfma_f32_16x16x32_bf16(a, bh[1][ks], ah1, 0, 0, 0);
        al1 = __builtin_amdgcn_mfma_f32_16x16x32_bf16(a, bl[1][ks], al1, 0, 0, 0);
      }
      #pragma unroll
      for (int reg = 0; reg < 4; ++reg) {
        int ii = q * 4 + reg;                // i-row within tile
        if (ii < IS) {
          float bv = bias[i0 + ii];
          res[(w * 32 + c) * 17 + ii]      = ah0[reg] + al0[reg] + bv;
          res[(w * 32 + 16 + c) * 17 + ii] = ah1[reg] + al1[reg] + bv;
        }
      }
    }
    // prologue: current-ic VMEM half (q-cols 64..127) into registers
    {
      const unsigned short* v0src = vhi + (size_t)i0 * (kH2 * kH2);
      #pragma unroll
      for (int pt = 0; pt < 8; ++pt) {
        int p = pt * 16 + c;
        vg[pt][0] = *(const bf16x8*)(v0src + (size_t)p * kH2 + 64 + q * 8);
        vg[pt][1] = *(const bf16x8*)(v0src + (size_t)p * kH2 + 96 + q * 8);
      }
    }
  }

  // V_i half-staging (q<64): XOR-chunk swizzle, global_load_lds width=16
  auto stageV = [&](int i, int buf) {
    const unsigned short* vsrc = vhi + (size_t)i * (kH2 * kH2);
    #pragma unroll
    for (int r = 0; r < 4; ++r) {
      int chunk = w * 256 + r * 64 + lane;   // 1024 phys 16B chunks (16 KB)
      int p  = chunk >> 3;                   // 8 chunks per 128B half-row
      int pc = chunk & 7;
      int cc = pc ^ (p & 7);                 // logical chunk in V row p (q<64)
      const unsigned short* g = vsrc + p * kH2 + cc * 8;
      __builtin_amdgcn_global_load_lds(
          (const __attribute__((address_space(1))) unsigned int*)g,
          (__attribute__((address_space(3))) unsigned int*)
              ((char*)&Vs[buf][0] + (size_t)(w * 256 + r * 64) * 16),
          16, 0, 0);
    }
  };

  stageV(i0, 0);
  __syncthreads();

  for (int ic = 0; ic < IS; ++ic) {
    // issue next LDS-half staging early; latency hides under this ic's compute
    if (ic + 1 < IS) stageV(i0 + ic + 1, (ic + 1) & 1);
    if (has_rows) {
      const char* vbase = (const char*)&Vs[ic & 1][0];
      const int inext = (ic + 1 < IS) ? (ic + 1) : ic;   // clamp (redundant last)
      const unsigned short* vnext = vhi + (size_t)(i0 + inext) * (kH2 * kH2);
      float g0 = 0.f, g1 = 0.f;
      #pragma unroll
      for (int pt = 0; pt < 8; ++pt) {
        int p = pt * 16 + c;
        f32x4 a0 = {0.f,0.f,0.f,0.f}, a1 = a0, a2 = a0, a3 = a0;
        // VMEM half from registers (ks = 2,3)
        a0 = __builtin_amdgcn_mfma_f32_16x16x32_bf16(vg[pt][0], bh[0][2], a0, 0, 0, 0);
        a1 = __builtin_amdgcn_mfma_f32_16x16x32_bf16(vg[pt][0], bl[0][2], a1, 0, 0, 0);
        a2 = __builtin_amdgcn_mfma_f32_16x16x32_bf16(vg[pt][0], bh[1][2], a2, 0, 0, 0);
        a3 = __builtin_amdgcn_mfma_f32_16x16x32_bf16(vg[pt][0], bl[1][2], a3, 0, 0, 0);
        a0 = __builtin_amdgcn_mfma_f32_16x16x32_bf16(vg[pt][1], bh[0][3], a0, 0, 0, 0);
        a1 = __builtin_amdgcn_mfma_f32_16x16x32_bf16(vg[pt][1], bl[0][3], a1, 0, 0, 0);
        a2 = __builtin_amdgcn_mfma_f32_16x16x32_bf16(vg[pt][1], bh[1][3], a2, 0, 0, 0);
        a3 = __builtin_amdgcn_mfma_f32_16x16x32_bf16(vg[pt][1], bl[1][3], a3, 0, 0, 0);
        // prefetch NEXT ic's VMEM half (used one full ic later; WAR-safe)
        vg[pt][0] = *(const bf16x8*)(vnext + (size_t)p * kH2 + 64 + q * 8);
        vg[pt][1] = *(const bf16x8*)(vnext + (size_t)p * kH2 + 96 + q * 8);
        // LDS half (ks = 0,1)
        #pragma unroll
        for (int ks = 0; ks < 2; ++ks) {
          int cc = (ks * 4 + q) ^ (p & 7);   // swizzled 16B chunk in half-row
          bf16x8 vf = *(const bf16x8*)(vbase + (size_t)p * 128 + cc * 16);
          a0 = __builtin_amdgcn_mfma_f32_16x16x32_bf16(vf, bh[0][ks], a0, 0, 0, 0);
          a1 = __builtin_amdgcn_mfma_f32_16x16x32_bf16(vf, bl[0][ks], a1, 0, 0, 0);
          a2 = __builtin_amdgcn_mfma_f32_16x16x32_bf16(vf, bh[1][ks], a2, 0, 0, 0);
          a3 = __builtin_amdgcn_mfma_f32_16x16x32_bf16(vf, bl[1][ks], a3, 0, 0, 0);
        }
        f32x4 d0 = a0 + a1, d1 = a2 + a3;    // hi+lo
        f32x4 cr0 = Cred[0][pt], cr1 = Cred[1][pt];
        g0 = fmaf(cr0[0], d0[0], g0); g0 = fmaf(cr0[1], d0[1], g0);
        g0 = fmaf(cr0[2], d0[2], g0); g0 = fmaf(cr0[3], d0[3], g0);
        g1 = fmaf(cr1[0], d1[0], g1); g1 = fmaf(cr1[1], d1[1], g1);
        g1 = fmaf(cr1[2], d1[2], g1); g1 = fmaf(cr1[3], d1[3], g1);
      }
      // sum over quads (p covers all 128 after this)
      g0 += __shfl_xor(g0, 16); g0 += __shfl_xor(g0, 32);
      g1 += __shfl_xor(g1, 16); g1 += __shfl_xor(g1, 32);
      if (q == 0)      res[(w * 32 + c) * 17 + ic]      += g0;
      else if (q == 1) res[(w * 32 + 16 + c) * 17 + ic] += g1;
    }
    // single barrier per ic: drains stage vmcnt (issued early, overlapped),
    // orders Vs half-buffer reuse + res writes + vg prefetch completion
    __syncthreads();
  }

  // epilogue: tanh + store (coalesced over i within row)
  const int sh = __builtin_ctz(IS);
  for (int idx = t; idx < Mrows * IS; idx += 256) {
    int m = idx >> sh, ii = idx & (IS - 1);
    out[(size_t)(m0 + m) * kH + i0 + ii] = tanhf(res[m * 17 + ii]);
  }
}

// ---- head: logits = root @ Wout + bout; log_softmax ----
__global__ void head_k(const float* __restrict__ root,
                       const float* __restrict__ Wout,
                       const float* __restrict__ bout,
                       float* __restrict__ out) {
  int b = threadIdx.x;
  float l[kOut];
  #pragma unroll
  for (int o = 0; o < kOut; ++o) l[o] = bout[o];
  for (int h = 0; h < kH; ++h) {
    float r = root[b * kH + h];
    #pragma unroll
    for (int o = 0; o < kOut; ++o) l[o] = fmaf(r, Wout[h * kOut + o], l[o]);
  }
  float mx = l[0];
  #pragma unroll
  for (int o = 1; o < kOut; ++o) mx = fmaxf(mx, l[o]);
  float s = 0.f;
  #pragma unroll
  for (int o = 0; o < kOut; ++o) s += expf(l[o] - mx);
  float lse = logf(s);
  #pragma unroll
  for (int o = 0; o < kOut; ++o) out[b * kOut + o] = l[o] - mx - lse;
}

extern "C" void kernel_launch(void* const* d_in, const int* in_sizes, int n_in,
                              void* d_out, int out_size, void* d_ws, size_t ws_size,
                              hipStream_t stream) {
  const int*   tokens = (const int*)  d_in[0];
  const float* embed  = (const float*)d_in[1];
  const float* V      = (const float*)d_in[2];
  const float* W      = (const float*)d_in[3];
  const float* bias   = (const float*)d_in[4];
  const float* Wout   = (const float*)d_in[5];
  const float* bout   = (const float*)d_in[6];
  float* out = (float*)d_out;

  // ws layout: vhi 2MB | wt 16KB | bufA 4MB | bufB 2MB  (~8.3 MB total)
  char* ws = (char*)d_ws;
  unsigned short* vhi = (unsigned short*)ws;
  unsigned short* wt  = (unsigned short*)(ws + 2097152);
  float* bufA = (float*)(ws + 2097152 + 16384);
  float* bufB = (float*)(ws + 2097152 + 16384 + 4194304);

  int nprep = kH * kH2 * kH2 + kH * kH2;
  prep_k<<<dim3((nprep + 255) / 256), 256, 0, stream>>>(V, W, vhi, wt);

  const float* cur = nullptr;
  float* nxt = bufA;
  bool first = true;
  for (int Nout = 256; Nout >= 1; Nout >>= 1) {
    int M = kB * Nout;
    int gx = (M + 127) / 128;
    int IS = gx / 8; if (IS < 1) IS = 1; if (IS > 16) IS = 16;
    dim3 grid(gx, 64 / IS);
    if (first)
      combine2_k<true ><<<grid, 256, 0, stream>>>(nullptr, tokens, embed, vhi, wt, bias, nxt, M, IS);
    else
      combine2_k<false><<<grid, 256, 0, stream>>>(cur, nullptr, nullptr, vhi, wt, bias, nxt, M, IS);
    first = false;
    cur = nxt;
    nxt = (nxt == bufA) ? bufB : bufA;
  }
  head_k<<<1, 64, 0, stream>>>(cur, Wout, bout, out);   // cur == bufA (9 levels)
}

// Round 10
// 268.304 us; speedup vs baseline: 3.9911x; 1.3327x over previous
//
#include <hip/hip_runtime.h>
#include <cmath>

// B=64, L=512, H=64, 2H=128, OUT=5
static constexpr int kB = 64, kL = 512, kH = 64, kH2 = 128, kOut = 5;

typedef short bf16x8 __attribute__((ext_vector_type(8)));
typedef float f32x4  __attribute__((ext_vector_type(4)));

__device__ __forceinline__ unsigned short f2bf(float f) {
  unsigned u = __float_as_uint(f);
  unsigned r = (u + 0x7FFFu + ((u >> 16) & 1u)) >> 16;   // RNE
  return (unsigned short)r;
}

__device__ __forceinline__ void cvt8(const f32x4& v0, const f32x4& v1,
                                     bf16x8& hi, bf16x8& lo) {
  #pragma unroll
  for (int j = 0; j < 4; ++j) {
    unsigned short h0 = f2bf(v0[j]);
    unsigned short h1 = f2bf(v1[j]);
    hi[j]     = (short)h0;
    hi[j + 4] = (short)h1;
    lo[j]     = (short)f2bf(v0[j] - __uint_as_float(((unsigned)h0) << 16));
    lo[j + 4] = (short)f2bf(v1[j] - __uint_as_float(((unsigned)h1) << 16));
  }
}

// ---- prepass: V fp32 -> bf16 (row-major [i][p][q]); W -> Wt bf16 [i][p] ----
__global__ void prep_k(const float* __restrict__ V, const float* __restrict__ W,
                       unsigned short* __restrict__ vhi, unsigned short* __restrict__ wt) {
  int idx = blockIdx.x * 256 + threadIdx.x;
  if (idx < kH * kH2 * kH2) {
    vhi[idx] = f2bf(V[idx]);
  } else {
    int widx = idx - kH * kH2 * kH2;
    if (widx < kH * kH2) {
      int i = widx >> 7, p = widx & 127;
      wt[widx] = f2bf(W[p * kH + i]);      // Wt[i][p] = W[p][i]
    }
  }
}

// ---- fused combine level: out[m,i] = tanh(c_m^T V_i c_m + (W^T c_m)_i + b_i)
// MFMA orientation: D[p, m] = sum_q V_i[p,q] * C[m,q]  (A = V_i, B = C hi/lo)
// then R[m,i] = sum_p C[m,p] * D[p,m] via per-lane dot + xor16/xor32 butterfly.
// 2-IC PHASES: stage TWO V matrices (64 KB, 2 blocks/CU at 72.5 KB LDS),
// compute both ics between one barrier pair. Halves barrier events and
// stage-drain exposures per ic vs the R2 structure; math is bit-identical.
template<bool FIRST>
__global__ __launch_bounds__(256) void combine2_k(
    const float* __restrict__ in, const int* __restrict__ tokens,
    const float* __restrict__ embed, const unsigned short* __restrict__ vhi,
    const unsigned short* __restrict__ wt, const float* __restrict__ bias,
    float* __restrict__ out, int M, int IS)
{
  __shared__ unsigned short Vs[2][kH2 * kH2]; // 2 x 32 KB, XOR-swizzled chunks
  __shared__ float res[128 * 17];             // Wx+bias, then += xVx; pad 17

  const int t = threadIdx.x;
  const int lane = t & 63, w = t >> 6;
  const int c = lane & 15, q = lane >> 4;    // c = B-col (node), q = quad
  const int m0 = (int)blockIdx.x * 128;
  const int i0 = (int)blockIdx.y * IS;
  const int Mrows = (M < 128) ? M : 128;
  const bool has_rows = (w * 32) < Mrows;

  bf16x8 bh[2][4], bl[2][4];   // C hi/lo B-fragments, [mtile][kstep]
  f32x4  Cred[2][8];           // C fp32 for the p-reduction, [mtile][ptile]

  if (has_rows) {
    #pragma unroll
    for (int mt = 0; mt < 2; ++mt) {
      int m = m0 + w * 32 + mt * 16 + c;     // this lane's node row
      const float* crow = nullptr;
      int tokA = 0, tokB = 0;
      if (FIRST) {                           // level 1: gather from embed
        int b = m >> 8, j = m & 255;         // Nout=256
        tokA = tokens[b * kL + 2 * j];
        tokB = tokens[b * kL + 2 * j + 1];
      } else {
        crow = in + (size_t)m * kH2;
      }
      #pragma unroll
      for (int ks = 0; ks < 4; ++ks) {       // B-frag: 8 contiguous q at lane's m
        int q0 = ks * 32 + q * 8;
        const float* src = FIRST
            ? (embed + (size_t)(q0 < 64 ? tokA : tokB) * kH + (q0 & 63))
            : (crow + q0);
        f32x4 v0 = *(const f32x4*)src;
        f32x4 v1 = *(const f32x4*)(src + 4);
        cvt8(v0, v1, bh[mt][ks], bl[mt][ks]);
      }
      #pragma unroll
      for (int pt = 0; pt < 8; ++pt) {       // reduction copy: C[m, pt*16+q*4 ..+4]
        int p0 = pt * 16 + q * 4;
        const float* src = FIRST
            ? (embed + (size_t)(p0 < 64 ? tokA : tokB) * kH + (p0 & 63))
            : (crow + p0);
        Cred[mt][pt] = *(const f32x4*)src;
      }
    }
    // Wx GEMM: D'[i, m] = sum_p Wt[i,p] * C[m,p]; res init = Wx + bias
    {
      int irow = i0 + c; if (irow > 63) irow = 63;
      f32x4 ah0 = {0.f,0.f,0.f,0.f}, al0 = ah0, ah1 = ah0, al1 = ah0;
      #pragma unroll
      for (int ks = 0; ks < 4; ++ks) {
        bf16x8 a = *(const bf16x8*)(wt + (size_t)irow * kH2 + ks * 32 + q * 8);
        ah0 = __builtin_amdgcn_mfma_f32_16x16x32_bf16(a, bh[0][ks], ah0, 0, 0, 0);
        al0 = __builtin_amdgcn_mfma_f32_16x16x32_bf16(a, bl[0][ks], al0, 0, 0, 0);
        ah1 = __builtin_amdgcn_mfma_f32_16x16x32_bf16(a, bh[1][ks], ah1, 0, 0, 0);
        al1 = __builtin_amdgcn_mfma_f32_16x16x32_bf16(a, bl[1][ks], al1, 0, 0, 0);
      }
      #pragma unroll
      for (int reg = 0; reg < 4; ++reg) {
        int ii = q * 4 + reg;                // i-row within tile
        if (ii < IS) {
          float bv = bias[i0 + ii];
          res[(w * 32 + c) * 17 + ii]      = ah0[reg] + al0[reg] + bv;
          res[(w * 32 + 16 + c) * 17 + ii] = ah1[reg] + al1[reg] + bv;
        }
      }
    }
  }

  // V_i staging: XOR-chunk swizzle, global_load_lds width=16, wave-uniform dest
  auto stageV = [&](int i, int buf) {
    const unsigned short* vsrc = vhi + (size_t)i * (kH2 * kH2);
    #pragma unroll
    for (int r = 0; r < 8; ++r) {
      int chunk = w * 512 + r * 64 + lane;   // physical 16B chunk in LDS
      int p  = chunk >> 4;
      int pc = chunk & 15;
      int cc = pc ^ (p & 7);                 // logical chunk in V row p
      const unsigned short* g = vsrc + p * kH2 + cc * 8;
      __builtin_amdgcn_global_load_lds(
          (const __attribute__((address_space(1))) unsigned int*)g,
          (__attribute__((address_space(3))) unsigned int*)
              ((char*)&Vs[buf][0] + (size_t)(w * 512 + r * 64) * 16),
          16, 0, 0);
    }
  };

  // one ic's bilinear accumulation out of buffer `buf`
  auto computeIC = [&](int ic, int buf) {
    const char* vbase = (const char*)&Vs[buf][0];
    float g0 = 0.f, g1 = 0.f;
    for (int pt = 0; pt < 8; ++pt) {
      f32x4 a0 = {0.f,0.f,0.f,0.f}, a1 = a0, a2 = a0, a3 = a0;
      #pragma unroll
      for (int ks = 0; ks < 4; ++ks) {
        int p  = pt * 16 + c;                // A-frag: V row p, 8 bf16 at q-chunk
        int cc = (ks * 4 + q) ^ (p & 7);     // swizzled chunk
        bf16x8 vf = *(const bf16x8*)(vbase + (size_t)p * 256 + cc * 16);
        a0 = __builtin_amdgcn_mfma_f32_16x16x32_bf16(vf, bh[0][ks], a0, 0, 0, 0);
        a1 = __builtin_amdgcn_mfma_f32_16x16x32_bf16(vf, bl[0][ks], a1, 0, 0, 0);
        a2 = __builtin_amdgcn_mfma_f32_16x16x32_bf16(vf, bh[1][ks], a2, 0, 0, 0);
        a3 = __builtin_amdgcn_mfma_f32_16x16x32_bf16(vf, bl[1][ks], a3, 0, 0, 0);
      }
      f32x4 d0 = a0 + a1, d1 = a2 + a3;      // hi+lo
      f32x4 cr0 = Cred[0][pt], cr1 = Cred[1][pt];
      g0 = fmaf(cr0[0], d0[0], g0); g0 = fmaf(cr0[1], d0[1], g0);
      g0 = fmaf(cr0[2], d0[2], g0); g0 = fmaf(cr0[3], d0[3], g0);
      g1 = fmaf(cr1[0], d1[0], g1); g1 = fmaf(cr1[1], d1[1], g1);
      g1 = fmaf(cr1[2], d1[2], g1); g1 = fmaf(cr1[3], d1[3], g1);
    }
    // sum over quads (p covers all 128 after this)
    g0 += __shfl_xor(g0, 16); g0 += __shfl_xor(g0, 32);
    g1 += __shfl_xor(g1, 16); g1 += __shfl_xor(g1, 32);
    if (q == 0)      res[(w * 32 + c) * 17 + ic]      += g0;
    else if (q == 1) res[(w * 32 + 16 + c) * 17 + ic] += g1;
  };

  if (IS >= 2) {
    stageV(i0, 0); stageV(i0 + 1, 1);
    __syncthreads();
    for (int icp = 0; icp < IS; icp += 2) {
      if (has_rows) {
        computeIC(icp, 0);
        computeIC(icp + 1, 1);
      }
      __syncthreads();                        // V reads + res writes done
      if (icp + 2 < IS) {
        stageV(i0 + icp + 2, 0); stageV(i0 + icp + 3, 1);
        __syncthreads();
      }
    }
  } else {
    stageV(i0, 0);
    __syncthreads();
    if (has_rows) computeIC(0, 0);
    __syncthreads();
  }

  // epilogue: tanh + store (coalesced over i within row)
  const int sh = __builtin_ctz(IS);
  for (int idx = t; idx < Mrows * IS; idx += 256) {
    int m = idx >> sh, ii = idx & (IS - 1);
    out[(size_t)(m0 + m) * kH + i0 + ii] = tanhf(res[m * 17 + ii]);
  }
}

// ---- head: logits = root @ Wout + bout; log_softmax ----
__global__ void head_k(const float* __restrict__ root,
                       const float* __restrict__ Wout,
                       const float* __restrict__ bout,
                       float* __restrict__ out) {
  int b = threadIdx.x;
  float l[kOut];
  #pragma unroll
  for (int o = 0; o < kOut; ++o) l[o] = bout[o];
  for (int h = 0; h < kH; ++h) {
    float r = root[b * kH + h];
    #pragma unroll
    for (int o = 0; o < kOut; ++o) l[o] = fmaf(r, Wout[h * kOut + o], l[o]);
  }
  float mx = l[0];
  #pragma unroll
  for (int o = 1; o < kOut; ++o) mx = fmaxf(mx, l[o]);
  float s = 0.f;
  #pragma unroll
  for (int o = 0; o < kOut; ++o) s += expf(l[o] - mx);
  float lse = logf(s);
  #pragma unroll
  for (int o = 0; o < kOut; ++o) out[b * kOut + o] = l[o] - mx - lse;
}

extern "C" void kernel_launch(void* const* d_in, const int* in_sizes, int n_in,
                              void* d_out, int out_size, void* d_ws, size_t ws_size,
                              hipStream_t stream) {
  const int*   tokens = (const int*)  d_in[0];
  const float* embed  = (const float*)d_in[1];
  const float* V      = (const float*)d_in[2];
  const float* W      = (const float*)d_in[3];
  const float* bias   = (const float*)d_in[4];
  const float* Wout   = (const float*)d_in[5];
  const float* bout   = (const float*)d_in[6];
  float* out = (float*)d_out;

  // ws layout: vhi 2MB | wt 16KB | bufA 4MB | bufB 2MB  (~8.3 MB total)
  char* ws = (char*)d_ws;
  unsigned short* vhi = (unsigned short*)ws;
  unsigned short* wt  = (unsigned short*)(ws + 2097152);
  float* bufA = (float*)(ws + 2097152 + 16384);
  float* bufB = (float*)(ws + 2097152 + 16384 + 4194304);

  int nprep = kH * kH2 * kH2 + kH * kH2;
  prep_k<<<dim3((nprep + 255) / 256), 256, 0, stream>>>(V, W, vhi, wt);

  const float* cur = nullptr;
  float* nxt = bufA;
  bool first = true;
  for (int Nout = 256; Nout >= 1; Nout >>= 1) {
    int M = kB * Nout;
    int gx = (M + 127) / 128;
    int IS = gx / 8; if (IS < 1) IS = 1; if (IS > 16) IS = 16;
    dim3 grid(gx, 64 / IS);
    if (first)
      combine2_k<true ><<<grid, 256, 0, stream>>>(nullptr, tokens, embed, vhi, wt, bias, nxt, M, IS);
    else
      combine2_k<false><<<grid, 256, 0, stream>>>(cur, nullptr, nullptr, vhi, wt, bias, nxt, M, IS);
    first = false;
    cur = nxt;
    nxt = (nxt == bufA) ? bufB : bufA;
  }
  head_k<<<1, 64, 0, stream>>>(cur, Wout, bout, out);   // cur == bufA (9 levels)
}

// Round 11
// 216.474 us; speedup vs baseline: 4.9467x; 1.2394x over previous
//
#include <hip/hip_runtime.h>
#include <cmath>

// B=64, L=512, H=64, 2H=128, OUT=5
static constexpr int kB = 64, kL = 512, kH = 64, kH2 = 128, kOut = 5;

typedef short bf16x8 __attribute__((ext_vector_type(8)));
typedef float f32x4  __attribute__((ext_vector_type(4)));

__device__ __forceinline__ unsigned short f2bf(float f) {
  unsigned u = __float_as_uint(f);
  unsigned r = (u + 0x7FFFu + ((u >> 16) & 1u)) >> 16;   // RNE
  return (unsigned short)r;
}

__device__ __forceinline__ void cvt8(const f32x4& v0, const f32x4& v1,
                                     bf16x8& hi, bf16x8& lo) {
  #pragma unroll
  for (int j = 0; j < 4; ++j) {
    unsigned short h0 = f2bf(v0[j]);
    unsigned short h1 = f2bf(v1[j]);
    hi[j]     = (short)h0;
    hi[j + 4] = (short)h1;
    lo[j]     = (short)f2bf(v0[j] - __uint_as_float(((unsigned)h0) << 16));
    lo[j + 4] = (short)f2bf(v1[j] - __uint_as_float(((unsigned)h1) << 16));
  }
}

// ---- prepass: V fp32 -> bf16 (row-major [i][p][q]); W -> Wt bf16 [i][p] ----
__global__ void prep_k(const float* __restrict__ V, const float* __restrict__ W,
                       unsigned short* __restrict__ vhi, unsigned short* __restrict__ wt) {
  int idx = blockIdx.x * 256 + threadIdx.x;
  if (idx < kH * kH2 * kH2) {
    vhi[idx] = f2bf(V[idx]);
  } else {
    int widx = idx - kH * kH2 * kH2;
    if (widx < kH * kH2) {
      int i = widx >> 7, p = widx & 127;
      wt[widx] = f2bf(W[p * kH + i]);      // Wt[i][p] = W[p][i]
    }
  }
}

// ---- fused combine level: out[m,i] = tanh(c_m^T V_i c_m + (W^T c_m)_i + b_i)
// MFMA orientation: D[p, m] = sum_q V_i[p,q] * C[m,q]  (A = V_i, B = C)
// then R[m,i] = sum_p C[m,p] * D[p,m] via per-lane dot + xor16/xor32 butterfly.
// 2-IC PHASES (measured best, R10). PRECISION TRADE (this round): xVx uses
// C-hi ONLY — V is bf16-only anyway, so C-lo's contribution is the same order
// as V's accepted rounding error. Halves the inner MFMA count (the largest
// measured pipe load, 42%). Wx keeps hi/lo (prologue-only, cheap).
template<bool FIRST>
__global__ __launch_bounds__(256) void combine2_k(
    const float* __restrict__ in, const int* __restrict__ tokens,
    const float* __restrict__ embed, const unsigned short* __restrict__ vhi,
    const unsigned short* __restrict__ wt, const float* __restrict__ bias,
    float* __restrict__ out, int M, int IS)
{
  __shared__ unsigned short Vs[2][kH2 * kH2]; // 2 x 32 KB, XOR-swizzled chunks
  __shared__ float res[128 * 17];             // Wx+bias, then += xVx; pad 17

  const int t = threadIdx.x;
  const int lane = t & 63, w = t >> 6;
  const int c = lane & 15, q = lane >> 4;    // c = B-col (node), q = quad
  const int m0 = (int)blockIdx.x * 128;
  const int i0 = (int)blockIdx.y * IS;
  const int Mrows = (M < 128) ? M : 128;
  const bool has_rows = (w * 32) < Mrows;

  bf16x8 bh[2][4], bl[2][4];   // C hi/lo B-fragments, [mtile][kstep]
  f32x4  Cred[2][8];           // C fp32 for the p-reduction, [mtile][ptile]

  if (has_rows) {
    #pragma unroll
    for (int mt = 0; mt < 2; ++mt) {
      int m = m0 + w * 32 + mt * 16 + c;     // this lane's node row
      const float* crow = nullptr;
      int tokA = 0, tokB = 0;
      if (FIRST) {                           // level 1: gather from embed
        int b = m >> 8, j = m & 255;         // Nout=256
        tokA = tokens[b * kL + 2 * j];
        tokB = tokens[b * kL + 2 * j + 1];
      } else {
        crow = in + (size_t)m * kH2;
      }
      #pragma unroll
      for (int ks = 0; ks < 4; ++ks) {       // B-frag: 8 contiguous q at lane's m
        int q0 = ks * 32 + q * 8;
        const float* src = FIRST
            ? (embed + (size_t)(q0 < 64 ? tokA : tokB) * kH + (q0 & 63))
            : (crow + q0);
        f32x4 v0 = *(const f32x4*)src;
        f32x4 v1 = *(const f32x4*)(src + 4);
        cvt8(v0, v1, bh[mt][ks], bl[mt][ks]);
      }
      #pragma unroll
      for (int pt = 0; pt < 8; ++pt) {       // reduction copy: C[m, pt*16+q*4 ..+4]
        int p0 = pt * 16 + q * 4;
        const float* src = FIRST
            ? (embed + (size_t)(p0 < 64 ? tokA : tokB) * kH + (p0 & 63))
            : (crow + p0);
        Cred[mt][pt] = *(const f32x4*)src;
      }
    }
    // Wx GEMM: D'[i, m] = sum_p Wt[i,p] * C[m,p]; res init = Wx + bias (hi+lo)
    {
      int irow = i0 + c; if (irow > 63) irow = 63;
      f32x4 ah0 = {0.f,0.f,0.f,0.f}, al0 = ah0, ah1 = ah0, al1 = ah0;
      #pragma unroll
      for (int ks = 0; ks < 4; ++ks) {
        bf16x8 a = *(const bf16x8*)(wt + (size_t)irow * kH2 + ks * 32 + q * 8);
        ah0 = __builtin_amdgcn_mfma_f32_16x16x32_bf16(a, bh[0][ks], ah0, 0, 0, 0);
        al0 = __builtin_amdgcn_mfma_f32_16x16x32_bf16(a, bl[0][ks], al0, 0, 0, 0);
        ah1 = __builtin_amdgcn_mfma_f32_16x16x32_bf16(a, bh[1][ks], ah1, 0, 0, 0);
        al1 = __builtin_amdgcn_mfma_f32_16x16x32_bf16(a, bl[1][ks], al1, 0, 0, 0);
      }
      #pragma unroll
      for (int reg = 0; reg < 4; ++reg) {
        int ii = q * 4 + reg;                // i-row within tile
        if (ii < IS) {
          float bv = bias[i0 + ii];
          res[(w * 32 + c) * 17 + ii]      = ah0[reg] + al0[reg] + bv;
          res[(w * 32 + 16 + c) * 17 + ii] = ah1[reg] + al1[reg] + bv;
        }
      }
    }
  }

  // V_i staging: XOR-chunk swizzle, global_load_lds width=16, wave-uniform dest
  auto stageV = [&](int i, int buf) {
    const unsigned short* vsrc = vhi + (size_t)i * (kH2 * kH2);
    #pragma unroll
    for (int r = 0; r < 8; ++r) {
      int chunk = w * 512 + r * 64 + lane;   // physical 16B chunk in LDS
      int p  = chunk >> 4;
      int pc = chunk & 15;
      int cc = pc ^ (p & 7);                 // logical chunk in V row p
      const unsigned short* g = vsrc + p * kH2 + cc * 8;
      __builtin_amdgcn_global_load_lds(
          (const __attribute__((address_space(1))) unsigned int*)g,
          (__attribute__((address_space(3))) unsigned int*)
              ((char*)&Vs[buf][0] + (size_t)(w * 512 + r * 64) * 16),
          16, 0, 0);
    }
  };

  // one ic's bilinear accumulation out of buffer `buf` (C-hi only)
  auto computeIC = [&](int ic, int buf) {
    const char* vbase = (const char*)&Vs[buf][0];
    float g0 = 0.f, g1 = 0.f;
    for (int pt = 0; pt < 8; ++pt) {
      f32x4 a0 = {0.f,0.f,0.f,0.f}, a2 = a0;
      #pragma unroll
      for (int ks = 0; ks < 4; ++ks) {
        int p  = pt * 16 + c;                // A-frag: V row p, 8 bf16 at q-chunk
        int cc = (ks * 4 + q) ^ (p & 7);     // swizzled chunk
        bf16x8 vf = *(const bf16x8*)(vbase + (size_t)p * 256 + cc * 16);
        a0 = __builtin_amdgcn_mfma_f32_16x16x32_bf16(vf, bh[0][ks], a0, 0, 0, 0);
        a2 = __builtin_amdgcn_mfma_f32_16x16x32_bf16(vf, bh[1][ks], a2, 0, 0, 0);
      }
      f32x4 cr0 = Cred[0][pt], cr1 = Cred[1][pt];
      g0 = fmaf(cr0[0], a0[0], g0); g0 = fmaf(cr0[1], a0[1], g0);
      g0 = fmaf(cr0[2], a0[2], g0); g0 = fmaf(cr0[3], a0[3], g0);
      g1 = fmaf(cr1[0], a2[0], g1); g1 = fmaf(cr1[1], a2[1], g1);
      g1 = fmaf(cr1[2], a2[2], g1); g1 = fmaf(cr1[3], a2[3], g1);
    }
    // sum over quads (p covers all 128 after this)
    g0 += __shfl_xor(g0, 16); g0 += __shfl_xor(g0, 32);
    g1 += __shfl_xor(g1, 16); g1 += __shfl_xor(g1, 32);
    if (q == 0)      res[(w * 32 + c) * 17 + ic]      += g0;
    else if (q == 1) res[(w * 32 + 16 + c) * 17 + ic] += g1;
  };

  if (IS >= 2) {
    stageV(i0, 0); stageV(i0 + 1, 1);
    __syncthreads();
    for (int icp = 0; icp < IS; icp += 2) {
      if (has_rows) {
        computeIC(icp, 0);
        computeIC(icp + 1, 1);
      }
      __syncthreads();                        // V reads + res writes done
      if (icp + 2 < IS) {
        stageV(i0 + icp + 2, 0); stageV(i0 + icp + 3, 1);
        __syncthreads();
      }
    }
  } else {
    stageV(i0, 0);
    __syncthreads();
    if (has_rows) computeIC(0, 0);
    __syncthreads();
  }

  // epilogue: tanh + store (coalesced over i within row)
  const int sh = __builtin_ctz(IS);
  for (int idx = t; idx < Mrows * IS; idx += 256) {
    int m = idx >> sh, ii = idx & (IS - 1);
    out[(size_t)(m0 + m) * kH + i0 + ii] = tanhf(res[m * 17 + ii]);
  }
}

// ---- head: logits = root @ Wout + bout; log_softmax ----
__global__ void head_k(const float* __restrict__ root,
                       const float* __restrict__ Wout,
                       const float* __restrict__ bout,
                       float* __restrict__ out) {
  int b = threadIdx.x;
  float l[kOut];
  #pragma unroll
  for (int o = 0; o < kOut; ++o) l[o] = bout[o];
  for (int h = 0; h < kH; ++h) {
    float r = root[b * kH + h];
    #pragma unroll
    for (int o = 0; o < kOut; ++o) l[o] = fmaf(r, Wout[h * kOut + o], l[o]);
  }
  float mx = l[0];
  #pragma unroll
  for (int o = 1; o < kOut; ++o) mx = fmaxf(mx, l[o]);
  float s = 0.f;
  #pragma unroll
  for (int o = 0; o < kOut; ++o) s += expf(l[o] - mx);
  float lse = logf(s);
  #pragma unroll
  for (int o = 0; o < kOut; ++o) out[b * kOut + o] = l[o] - mx - lse;
}

extern "C" void kernel_launch(void* const* d_in, const int* in_sizes, int n_in,
                              void* d_out, int out_size, void* d_ws, size_t ws_size,
                              hipStream_t stream) {
  const int*   tokens = (const int*)  d_in[0];
  const float* embed  = (const float*)d_in[1];
  const float* V      = (const float*)d_in[2];
  const float* W      = (const float*)d_in[3];
  const float* bias   = (const float*)d_in[4];
  const float* Wout   = (const float*)d_in[5];
  const float* bout   = (const float*)d_in[6];
  float* out = (float*)d_out;

  // ws layout: vhi 2MB | wt 16KB | bufA 4MB | bufB 2MB  (~8.3 MB total)
  char* ws = (char*)d_ws;
  unsigned short* vhi = (unsigned short*)ws;
  unsigned short* wt  = (unsigned short*)(ws + 2097152);
  float* bufA = (float*)(ws + 2097152 + 16384);
  float* bufB = (float*)(ws + 2097152 + 16384 + 4194304);

  int nprep = kH * kH2 * kH2 + kH * kH2;
  prep_k<<<dim3((nprep + 255) / 256), 256, 0, stream>>>(V, W, vhi, wt);

  const float* cur = nullptr;
  float* nxt = bufA;
  bool first = true;
  for (int Nout = 256; Nout >= 1; Nout >>= 1) {
    int M = kB * Nout;
    int gx = (M + 127) / 128;
    int IS = gx / 8; if (IS < 1) IS = 1; if (IS > 16) IS = 16;
    dim3 grid(gx, 64 / IS);
    if (first)
      combine2_k<true ><<<grid, 256, 0, stream>>>(nullptr, tokens, embed, vhi, wt, bias, nxt, M, IS);
    else
      combine2_k<false><<<grid, 256, 0, stream>>>(cur, nullptr, nullptr, vhi, wt, bias, nxt, M, IS);
    first = false;
    cur = nxt;
    nxt = (nxt == bufA) ? bufB : bufA;
  }
  head_k<<<1, 64, 0, stream>>>(cur, Wout, bout, out);   // cur == bufA (9 levels)
}